// Round 8
// baseline (832.767 us; speedup 1.0000x reference)
//
#include <hip/hip_runtime.h>
#include <hip/hip_bf16.h>
#include <stdint.h>

// Problem constants (from reference)
#define M_DIM 8192              // 4*2048 batch*seq rows
#define N_DIM 4096              // out_features
#define K_DIM 4096              // in_features
#define NOG   4096              // num out groups (out_group=1)
#define NIG   512               // num in groups (in_group=8)

typedef __bf16 bf16;
typedef __attribute__((ext_vector_type(8))) __bf16 bf16x8;   // 4 VGPRs — MFMA A/B frag
typedef __attribute__((ext_vector_type(4))) float f32x4;     // MFMA C/D frag

// Tiled bf16 layout for the B (weight) operand ("chunk order"):
//   tile(g, h) = rows [g*16,(g+1)*16) x cols [h*32,(h+1)*32)
//   stored as 64 consecutive 16-B chunks, chunk index c = kblk*16 + row
//   global chunk id = (g * 128 + h) * 64 + kblk * 16 + row.
// GEMM B-staging reads 1024 CONTIGUOUS bytes per gload16 (lane l -> chunk l)
// and LDS receives fragment-read order -> zero bank conflicts (measured 0).
// A is consumed directly from fp32; convert fused into staging, T14-pipelined
// one K-step ahead. ROUND-7 LESSON: hand-counted vmcnt(8) at the mid barrier
// depended on VMEM issue order the scheduler doesn't guarantee -> NaN. This
// version issues pf loads AFTER the mid barrier, so the mid barrier can use
// an order-robust vmcnt(0) while pf still rides across the END barrier.

// ---------------------------------------------------------------------------
// async global->LDS, 16 B per lane. LDS dest is wave-uniform base + lane*16.
__device__ __forceinline__ void gload16(const void* g, void* lds) {
    __builtin_amdgcn_global_load_lds(
        (__attribute__((address_space(1))) void*)g,
        (__attribute__((address_space(3))) void*)lds,
        16 /*size*/, 0 /*offset*/, 0 /*aux*/);
}

// ---------------------------------------------------------------------------
// Kernel 1: AQLM dequant into chunk-order tiles (grid-stride streamer).
__global__ __launch_bounds__(256) void k_dequant(const int* __restrict__ codes,
                                                 const float* __restrict__ cb,
                                                 const float* __restrict__ scales,
                                                 bf16* __restrict__ w) {
    const int total  = NOG * (K_DIM / 8);                // 2,097,152 chunks
    const int stride = gridDim.x * 256;
    for (int id = blockIdx.x * 256 + threadIdx.x; id < total; id += stride) {
        const int r    = id & 15;
        const int kblk = (id >> 4) & 3;
        const int h    = (id >> 6) & 127;
        const int g    = id >> 13;
        const int o    = g * 16 + r;
        const int iG   = h * 4 + kblk;
        const unsigned code = (unsigned)codes[o * NIG + iG];
        const float s = scales[o];
        const float4* e = (const float4*)(cb + (size_t)code * 8);
        float4 e0 = e[0], e1 = e[1];
        bf16x8 v;
        v[0] = (bf16)(e0.x * s); v[1] = (bf16)(e0.y * s);
        v[2] = (bf16)(e0.z * s); v[3] = (bf16)(e0.w * s);
        v[4] = (bf16)(e1.x * s); v[5] = (bf16)(e1.y * s);
        v[6] = (bf16)(e1.z * s); v[7] = (bf16)(e1.w * s);
        ((bf16x8*)w)[id] = v;
    }
}

// ---------------------------------------------------------------------------
// Kernel 2: C[m,n] = sum_k A32[m,k]*B[n,k] + bias[n]; A fp32 row-major,
// B chunk-order bf16. Round-0 GEMM structure (48 KB LDS, 2 blocks/CU, m114
// inter-block overlap) with ORDER-ROBUST T14 A-staging:
//   top of iter ks: {B gload16 x4} {cvt+ds_write A(ks) from pf regs — the
//     compiler's dataflow s_waitcnt drains the pf loads issued LAST iter's
//     MFMA region, so their latency was hidden under ~700 cyc of MFMA}
//   mid: s_waitcnt vmcnt(0) lgkmcnt(0); s_barrier   [only the 4 B gloads
//     can still be outstanding here -> vmcnt(0) is cheap AND order-robust]
//   MFMA pass h0 -> {issue ALL pf loads for ks+1} -> MFMA pass h1
//   end: s_waitcnt lgkmcnt(0); s_barrier            [frag reads drained
//     before LDS overwrite; pf loads deliberately stay in flight]
// No hand-counted vmcnt anywhere -> no issue-order dependence (round-7 bug).
#define BM 256
#define BN 128
#define BK 64
#define KSTEPS (K_DIM / BK)

__global__ __launch_bounds__(256, 2) void k_gemm_fused(
    const float* __restrict__ A32,   // [M_DIM, K_DIM] fp32 row-major
    const bf16* __restrict__ B,      // chunk-order tiled [256 groups][128 halves]
    const float* __restrict__ bias,  // [N_DIM]
    float* __restrict__ C)           // [M_DIM, N_DIM] row-major
{
    __shared__ __align__(16) bf16 As[BM * BK];   // 32 KB
    __shared__ __align__(16) bf16 Bs[BN * BK];   // 16 KB

    const int tid  = threadIdx.x;
    const int wave = tid >> 6;         // 0..3
    const int lane = tid & 63;
    const int quad = lane >> 4;        // 0..3 (= kblk for staging)
    const int l16  = lane & 15;        // (= row-in-group for staging)

    // XCD-chunked bijective swizzle (T1): 1024 blocks, 1024%8==0. Each XCD
    // gets 128 consecutive logical tiles = 4 full M-rows of tiles -> the 32
    // blocks sharing an A row-panel co-reside on one XCD's L2 (attacks the
    // ~4.4x A re-fetch measured in round 6).
    const int bid = blockIdx.y * 32 + blockIdx.x;
    const int swz = (bid & 7) * 128 + (bid >> 3);
    const int bx  = swz & 31;          // logical N tile (0..31)
    const int by  = swz >> 5;          // logical M tile (0..31)

    const int bn0 = bx * BN;
    const int bm0 = by * BM;
    const int wm = (wave >> 1) * 128;  // wave's 128x64 subtile
    const int wn = (wave & 1) * 64;

    // A staging sources (fp32): lane l covers chunk l of each group-half.
    const float* pA32[4];
    #pragma unroll
    for (int gi = 0; gi < 4; ++gi) {
        const int G = by * 16 + wave * 4 + gi;             // A group (16 rows)
        pA32[gi] = A32 + (size_t)(G * 16 + l16) * K_DIM + quad * 8;
    }
    // B staging sources: lane l fetches chunk l of each group-half tile.
    const bf16* pB[2];
    #pragma unroll
    for (int gi = 0; gi < 2; ++gi) {
        const int g = bx * 8 + wave * 2 + gi;              // B group
        pB[gi] = B + ((size_t)g * 8192 + lane) * 8;
    }
    bf16* AsW = As + wave * 4096;      // wave's 4 A-groups (4*2*512 elems)
    bf16* BsW = Bs + wave * 2048;      // wave's 2 B-groups

    const int gA0 = (wave >> 1) * 8;   // first A group this wave reads
    const int gB0 = (wave & 1) * 4;    // first B group

    f32x4 acc[8][4] = {};
    float4 pf0[4][2], pf1[4][2];       // prefetch regs: h0 / h1 per group

    // Prologue: prefetch A(ks=0), both halves (dataflow-waited at iter 0).
    #pragma unroll
    for (int gi = 0; gi < 4; ++gi) {
        const float* pa = pA32[gi];
        pf0[gi][0] = *(const float4*)(pa);
        pf0[gi][1] = *(const float4*)(pa + 4);
        pf1[gi][0] = *(const float4*)(pa + 32);
        pf1[gi][1] = *(const float4*)(pa + 36);
    }

    for (int ks = 0; ks < KSTEPS; ++ks) {
        // ---- B staging: async global->LDS ----
        #pragma unroll
        for (int gi = 0; gi < 2; ++gi) {
            gload16(pB[gi],       BsW + gi * 1024);
            gload16(pB[gi] + 512, BsW + gi * 1024 + 512);
            pB[gi] += 1024;
        }
        // ---- A: cvt + chunk-order ds_write from pf (loaded last iter) ----
        #pragma unroll
        for (int gi = 0; gi < 4; ++gi) {
            float4 f0 = pf0[gi][0], f1 = pf0[gi][1];
            float4 f2 = pf1[gi][0], f3 = pf1[gi][1];
            bf16x8 c0, c1;
            c0[0] = (bf16)f0.x; c0[1] = (bf16)f0.y; c0[2] = (bf16)f0.z; c0[3] = (bf16)f0.w;
            c0[4] = (bf16)f1.x; c0[5] = (bf16)f1.y; c0[6] = (bf16)f1.z; c0[7] = (bf16)f1.w;
            c1[0] = (bf16)f2.x; c1[1] = (bf16)f2.y; c1[2] = (bf16)f2.z; c1[3] = (bf16)f2.w;
            c1[4] = (bf16)f3.x; c1[5] = (bf16)f3.y; c1[6] = (bf16)f3.z; c1[7] = (bf16)f3.w;
            ((bf16x8*)AsW)[gi * 128 + lane]      = c0;   // half 0, chunk=lane
            ((bf16x8*)AsW)[gi * 128 + 64 + lane] = c1;   // half 1, chunk=lane
        }
        // mid barrier: ORDER-ROBUST full drain. Only this iter's 4 B gloads
        // can be outstanding (pf loads were consumed by the cvt above via
        // the compiler's dataflow wait) -> vmcnt(0) is cheap here.
        asm volatile("s_waitcnt vmcnt(0) lgkmcnt(0)\n\ts_barrier" ::: "memory");

        // ---- fragment reads + MFMA pass h0 ----
        bf16x8 bq0[4], bq1[4];
        #pragma unroll
        for (int t = 0; t < 4; ++t) {
            bq0[t] = *(const bf16x8*)(Bs + (size_t)(gB0 + t) * 1024 + lane * 8);
            bq1[t] = *(const bf16x8*)(Bs + (size_t)(gB0 + t) * 1024 + 512 + lane * 8);
        }
        #pragma unroll
        for (int i = 0; i < 8; ++i) {
            bf16x8 a0 = *(const bf16x8*)(As + (size_t)(gA0 + i) * 1024 + lane * 8);
            #pragma unroll
            for (int j = 0; j < 4; ++j)
                acc[i][j] = __builtin_amdgcn_mfma_f32_16x16x32_bf16(
                    a0, bq0[j], acc[i][j], 0, 0, 0);
        }
        // ---- T14: issue prefetch for ks+1 (hidden under h1 MFMA pass +
        //      end barrier + next top; rides across the END barrier) ----
        const int kn = (ks + 1 < KSTEPS) ? ks + 1 : KSTEPS - 1;   // clamped tail
        #pragma unroll
        for (int gi = 0; gi < 4; ++gi) {
            const float* pa = pA32[gi] + kn * 64;
            pf0[gi][0] = *(const float4*)(pa);
            pf0[gi][1] = *(const float4*)(pa + 4);
            pf1[gi][0] = *(const float4*)(pa + 32);
            pf1[gi][1] = *(const float4*)(pa + 36);
        }
        // ---- MFMA pass h1 ----
        #pragma unroll
        for (int i = 0; i < 8; ++i) {
            bf16x8 a1 = *(const bf16x8*)(As + (size_t)(gA0 + i) * 1024 + 512 + lane * 8);
            #pragma unroll
            for (int j = 0; j < 4; ++j)
                acc[i][j] = __builtin_amdgcn_mfma_f32_16x16x32_bf16(
                    a1, bq1[j], acc[i][j], 0, 0, 0);
        }
        // end barrier: frag reads drained (lgkm) before next overwrite; pf
        // loads (vmcnt) deliberately stay in flight.
        asm volatile("s_waitcnt lgkmcnt(0)\n\ts_barrier" ::: "memory");
    }

    // Epilogue: C/D layout col = lane&15, row = quad*4 + reg  [m89/m91-verified]
    #pragma unroll
    for (int j = 0; j < 4; ++j) {
        const int gn = bn0 + wn + j * 16 + l16;
        const float bz = bias[gn];
        #pragma unroll
        for (int i = 0; i < 8; ++i) {
            float* cp = C + (size_t)(bm0 + wm + i * 16 + quad * 4) * N_DIM + gn;
            #pragma unroll
            for (int r = 0; r < 4; ++r)
                cp[(size_t)r * N_DIM] = acc[i][j][r] + bz;
        }
    }
}

// ---------------------------------------------------------------------------
extern "C" void kernel_launch(void* const* d_in, const int* in_sizes, int n_in,
                              void* d_out, int out_size, void* d_ws, size_t ws_size,
                              hipStream_t stream) {
    const float* input     = (const float*)d_in[0];   // [4,2048,4096]
    const int*   codes     = (const int*)d_in[1];     // [4096,512,1]
    const float* codebooks = (const float*)d_in[2];   // [1,65536,1,8]
    const float* scales    = (const float*)d_in[3];   // [4096]
    const float* bias      = (const float*)d_in[4];   // [4096]
    float* out = (float*)d_out;                        // [4,2048,4096]

    // Workspace: only W_tiled (33.5 MB); fully written by dequant before the
    // GEMM reads it, so the 0xAA poison is irrelevant.
    bf16* Wbf = (bf16*)d_ws;

    (void)in_sizes; (void)n_in; (void)out_size; (void)ws_size;

    // 1) dequantize W -> bf16, chunk-order tiled (grid-stride streamer).
    k_dequant<<<dim3(2048), 256, 0, stream>>>(codes, codebooks, scales, Wbf);

    // 2) fused convert+GEMM with order-robust T14 A-prefetch pipeline.
    {
        dim3 g(N_DIM / BN, M_DIM / BM);   // (32, 32)
        k_gemm_fused<<<g, 256, 0, stream>>>(input, Wbf, bias, out);
    }
}